// Round 1
// baseline (4577.821 us; speedup 1.0000x reference)
//
#include <hip/hip_runtime.h>

// Problem constants (match reference)
#define CCH 128      // FEATURE_DIM
#define HID 128      // HIDDEN
#define NCP 25
#define HH  128      // plane H
#define WW  128      // plane W

// Bilinear sample of one channel from a (C,H,W) plane, align_corners=True,
// border-clamped. u -> W axis, v -> H axis.
__device__ __forceinline__ float bilin(const float* __restrict__ pl, int c, float u, float v) {
    float x = fminf(fmaxf(u, 0.f), 1.f) * (float)(WW - 1);
    float y = fminf(fmaxf(v, 0.f), 1.f) * (float)(HH - 1);
    int x0 = (int)floorf(x); x0 = x0 > (WW - 2) ? (WW - 2) : x0;
    int y0 = (int)floorf(y); y0 = y0 > (HH - 2) ? (HH - 2) : y0;
    float wx = x - (float)x0;
    float wy = y - (float)y0;
    const float* p = pl + ((size_t)c << 14) + (y0 << 7) + x0;
    float f00 = p[0];
    float f01 = p[1];
    float f10 = p[WW];
    float f11 = p[WW + 1];
    float top = f00 * (1.f - wx) + f01 * wx;
    float bot = f10 * (1.f - wx) + f11 * wx;
    return top * (1.f - wy) + bot * wy;
}

__global__ __launch_bounds__(128) void equi_attn_kernel(
    const float* __restrict__ qp,    // (bs, ns, 9)
    const float* __restrict__ cxz,   // (bs, C, H, W)
    const float* __restrict__ cxy,
    const float* __restrict__ cyz,
    const float* __restrict__ cp,    // (NCP, 3)
    const float* __restrict__ Wv,    // (C, HID)
    const float* __restrict__ bv,    // (HID)
    const float* __restrict__ Ww,    // (C, NCP)
    const float* __restrict__ bw,    // (NCP)
    const float* __restrict__ Wo,    // (HID, C)
    const float* __restrict__ bo,    // (C)
    float* __restrict__ out,         // (bs, ns, C)
    int ns)
{
    const int q   = blockIdx.x;      // b*ns + n
    const int b   = q / ns;
    const int tid = threadIdx.x;     // channel / hidden index

    const size_t planeStride = (size_t)CCH * HH * WW;
    const float* pxz = cxz + (size_t)b * planeStride;
    const float* pxy = cxy + (size_t)b * planeStride;
    const float* pyz = cyz + (size_t)b * planeStride;

    const float* qptr = qp + (size_t)q * 9;
    const float px = qptr[0], py = qptr[1], pz = qptr[2];
    const float a1x = qptr[3], a1y = qptr[4], a1z = qptr[5];
    const float a2x = qptr[6], a2y = qptr[7], a2z = qptr[8];

    // rot6d -> matrix (Gram-Schmidt); rows b1,b2,b3
    float n1 = rsqrtf(a1x * a1x + a1y * a1y + a1z * a1z);
    float b1x = a1x * n1, b1y = a1y * n1, b1z = a1z * n1;
    float dd = b1x * a2x + b1y * a2y + b1z * a2z;
    float u2x = a2x - dd * b1x, u2y = a2y - dd * b1y, u2z = a2z - dd * b1z;
    float n2 = rsqrtf(u2x * u2x + u2y * u2y + u2z * u2z);
    float b2x = u2x * n2, b2y = u2y * n2, b2z = u2z * n2;
    float b3x = b1y * b2z - b1z * b2y;
    float b3y = b1z * b2x - b1x * b2z;
    float b3z = b1x * b2y - b1y * b2x;

    __shared__ float sFeat[CCH];
    __shared__ float sW[32];
    __shared__ float sWsum[CCH];
    __shared__ float sPre[HID];

    // feature[c] for this query
    float feat = bilin(pxz, tid, px, pz) + bilin(pxy, tid, px, py) + bilin(pyz, tid, py, pz);
    sFeat[tid] = feat;
    __syncthreads();

    // weights[g] = feature . Ww[:,g] + bw[g]
    if (tid < NCP) {
        float acc = bw[tid];
        #pragma unroll 8
        for (int c = 0; c < CCH; ++c)
            acc += sFeat[c] * Ww[c * NCP + tid];
        sW[tid] = acc;
    }
    __syncthreads();

    float sw = 0.f;
    #pragma unroll
    for (int g = 0; g < NCP; ++g) sw += sW[g];

    // wsum[c] = sum_g weights[g] * sf[g][c]
    float wacc = 0.f;
    for (int g = 0; g < NCP; ++g) {
        float cx = cp[g * 3 + 0], cy = cp[g * 3 + 1], cz = cp[g * 3 + 2];
        float ax = px + b1x * cx + b1y * cy + b1z * cz;
        float ay = py + b2x * cx + b2y * cy + b2z * cz;
        float az = pz + b3x * cx + b3y * cy + b3z * cz;
        float s = bilin(pxz, tid, ax, az) + bilin(pxy, tid, ax, ay) + bilin(pyz, tid, ay, az);
        wacc += sW[g] * s;
    }
    sWsum[tid] = wacc;
    __syncthreads();

    // pre[h] = sw*bv[h] + sum_c wsum[c] * Wv[c][h]
    float pre = sw * bv[tid];
    #pragma unroll 8
    for (int c = 0; c < CCH; ++c)
        pre += sWsum[c] * Wv[c * HID + tid];
    sPre[tid] = pre;
    __syncthreads();

    // out[c] = bo[c] + feature[c] + sum_h pre[h] * Wo[h][c]
    float o = bo[tid] + feat;
    #pragma unroll 8
    for (int h = 0; h < HID; ++h)
        o += sPre[h] * Wo[h * CCH + tid];
    out[(size_t)q * CCH + tid] = o;
}

extern "C" void kernel_launch(void* const* d_in, const int* in_sizes, int n_in,
                              void* d_out, int out_size, void* d_ws, size_t ws_size,
                              hipStream_t stream) {
    const float* qp  = (const float*)d_in[0];
    const float* cxz = (const float*)d_in[1];
    const float* cxy = (const float*)d_in[2];
    const float* cyz = (const float*)d_in[3];
    const float* cp  = (const float*)d_in[4];
    const float* Wv  = (const float*)d_in[5];
    const float* bv  = (const float*)d_in[6];
    const float* Ww  = (const float*)d_in[7];
    const float* bw  = (const float*)d_in[8];
    const float* Wo  = (const float*)d_in[9];
    const float* bo  = (const float*)d_in[10];
    float* out = (float*)d_out;

    const int bs = in_sizes[1] / (CCH * HH * WW);
    const int ns = in_sizes[0] / (bs * 9);
    const int nq = bs * ns;

    equi_attn_kernel<<<nq, 128, 0, stream>>>(
        qp, cxz, cxy, cyz, cp, Wv, bv, Ww, bw, Wo, bo, out, ns);
}

// Round 2
// 471.772 us; speedup vs baseline: 9.7035x; 9.7035x over previous
//
#include <hip/hip_runtime.h>

#define CCH 128      // FEATURE_DIM (channels)
#define HID 128      // HIDDEN
#define NCP 25
#define HH  128      // plane H
#define WW  128      // plane W
#define NPIX (HH * WW)

// ---------------- Transpose (B,C,H,W) -> (B,H,W,C) ----------------
#define TDIM 32
__global__ __launch_bounds__(256) void transpose_cl_kernel(
    const float* __restrict__ in,   // (B, C, NPIX)
    float* __restrict__ out)        // (B, NPIX, C)
{
    __shared__ float tile[TDIM][TDIM + 1];
    const int b = blockIdx.z;
    const float* src = in + (size_t)b * CCH * NPIX;
    float* dst = out + (size_t)b * CCH * NPIX;
    const int n0 = blockIdx.x * TDIM;
    const int c0 = blockIdx.y * TDIM;
    const int tx = threadIdx.x;  // 0..31, along N on load, along C on store
    const int ty = threadIdx.y;  // 0..7

    #pragma unroll
    for (int i = 0; i < TDIM; i += 8)
        tile[ty + i][tx] = src[(size_t)(c0 + ty + i) * NPIX + (n0 + tx)];
    __syncthreads();
    #pragma unroll
    for (int i = 0; i < TDIM; i += 8)
        dst[(size_t)(n0 + ty + i) * CCH + (c0 + tx)] = tile[tx][ty + i];
}

// ---------------- Bilinear helpers ----------------
// Channel-last plane (NPIX, C): coalesced across tid=c.
__device__ __forceinline__ float bilin_cl(const float* __restrict__ pl, int c, float u, float v) {
    float x = fminf(fmaxf(u, 0.f), 1.f) * (float)(WW - 1);
    float y = fminf(fmaxf(v, 0.f), 1.f) * (float)(HH - 1);
    int x0 = (int)floorf(x); x0 = x0 > (WW - 2) ? (WW - 2) : x0;
    int y0 = (int)floorf(y); y0 = y0 > (HH - 2) ? (HH - 2) : y0;
    float wx = x - (float)x0;
    float wy = y - (float)y0;
    const float* p = pl + ((size_t)(y0 * WW + x0) << 7) + c;
    float f00 = p[0];
    float f01 = p[CCH];
    float f10 = p[WW * CCH];
    float f11 = p[WW * CCH + CCH];
    float top = f00 * (1.f - wx) + f01 * wx;
    float bot = f10 * (1.f - wx) + f11 * wx;
    return top * (1.f - wy) + bot * wy;
}

// Channel-first plane (C,H,W) — fallback when ws is too small.
__device__ __forceinline__ float bilin_cf(const float* __restrict__ pl, int c, float u, float v) {
    float x = fminf(fmaxf(u, 0.f), 1.f) * (float)(WW - 1);
    float y = fminf(fmaxf(v, 0.f), 1.f) * (float)(HH - 1);
    int x0 = (int)floorf(x); x0 = x0 > (WW - 2) ? (WW - 2) : x0;
    int y0 = (int)floorf(y); y0 = y0 > (HH - 2) ? (HH - 2) : y0;
    float wx = x - (float)x0;
    float wy = y - (float)y0;
    const float* p = pl + ((size_t)c << 14) + (y0 << 7) + x0;
    float f00 = p[0];
    float f01 = p[1];
    float f10 = p[WW];
    float f11 = p[WW + 1];
    float top = f00 * (1.f - wx) + f01 * wx;
    float bot = f10 * (1.f - wx) + f11 * wx;
    return top * (1.f - wy) + bot * wy;
}

// ---------------- Main fused kernel ----------------
template <bool CL>
__global__ __launch_bounds__(128) void equi_attn_kernel(
    const float* __restrict__ qp,    // (bs, ns, 9)
    const float* __restrict__ cxz,   // plane 0 (layout per CL)
    const float* __restrict__ cxy,
    const float* __restrict__ cyz,
    const float* __restrict__ cp,    // (NCP, 3)
    const float* __restrict__ Wv,    // (C, HID)
    const float* __restrict__ bv,
    const float* __restrict__ Ww,    // (C, NCP)
    const float* __restrict__ bw,
    const float* __restrict__ Wo,    // (HID, C)
    const float* __restrict__ bo,
    float* __restrict__ out,         // (bs, ns, C)
    int ns)
{
    const int q   = blockIdx.x;
    const int b   = q / ns;
    const int tid = threadIdx.x;     // channel / hidden index

    const size_t planeStride = (size_t)CCH * NPIX;
    const float* pxz = cxz + (size_t)b * planeStride;
    const float* pxy = cxy + (size_t)b * planeStride;
    const float* pyz = cyz + (size_t)b * planeStride;

    const float* qptr = qp + (size_t)q * 9;
    const float px = qptr[0], py = qptr[1], pz = qptr[2];
    const float a1x = qptr[3], a1y = qptr[4], a1z = qptr[5];
    const float a2x = qptr[6], a2y = qptr[7], a2z = qptr[8];

    // rot6d -> matrix (Gram-Schmidt); rows b1,b2,b3
    float n1 = rsqrtf(a1x * a1x + a1y * a1y + a1z * a1z);
    float b1x = a1x * n1, b1y = a1y * n1, b1z = a1z * n1;
    float dd = b1x * a2x + b1y * a2y + b1z * a2z;
    float u2x = a2x - dd * b1x, u2y = a2y - dd * b1y, u2z = a2z - dd * b1z;
    float n2 = rsqrtf(u2x * u2x + u2y * u2y + u2z * u2z);
    float b2x = u2x * n2, b2y = u2y * n2, b2z = u2z * n2;
    float b3x = b1y * b2z - b1z * b2y;
    float b3y = b1z * b2x - b1x * b2z;
    float b3z = b1x * b2y - b1y * b2x;

    __shared__ float sFeat[CCH];
    __shared__ float sW[32];
    __shared__ float sWsum[CCH];
    __shared__ float sPre[HID];

    float feat;
    if (CL)
        feat = bilin_cl(pxz, tid, px, pz) + bilin_cl(pxy, tid, px, py) + bilin_cl(pyz, tid, py, pz);
    else
        feat = bilin_cf(pxz, tid, px, pz) + bilin_cf(pxy, tid, px, py) + bilin_cf(pyz, tid, py, pz);
    sFeat[tid] = feat;
    __syncthreads();

    if (tid < NCP) {
        float acc = bw[tid];
        #pragma unroll 8
        for (int c = 0; c < CCH; ++c)
            acc += sFeat[c] * Ww[c * NCP + tid];
        sW[tid] = acc;
    }
    __syncthreads();

    float sw = 0.f;
    #pragma unroll
    for (int g = 0; g < NCP; ++g) sw += sW[g];

    float wacc = 0.f;
    for (int g = 0; g < NCP; ++g) {
        float cx = cp[g * 3 + 0], cy = cp[g * 3 + 1], cz = cp[g * 3 + 2];
        float ax = px + b1x * cx + b1y * cy + b1z * cz;
        float ay = py + b2x * cx + b2y * cy + b2z * cz;
        float az = pz + b3x * cx + b3y * cy + b3z * cz;
        float s;
        if (CL)
            s = bilin_cl(pxz, tid, ax, az) + bilin_cl(pxy, tid, ax, ay) + bilin_cl(pyz, tid, ay, az);
        else
            s = bilin_cf(pxz, tid, ax, az) + bilin_cf(pxy, tid, ax, ay) + bilin_cf(pyz, tid, ay, az);
        wacc += sW[g] * s;
    }
    sWsum[tid] = wacc;
    __syncthreads();

    float pre = sw * bv[tid];
    #pragma unroll 8
    for (int c = 0; c < CCH; ++c)
        pre += sWsum[c] * Wv[c * HID + tid];
    sPre[tid] = pre;
    __syncthreads();

    float o = bo[tid] + feat;
    #pragma unroll 8
    for (int h = 0; h < HID; ++h)
        o += sPre[h] * Wo[h * CCH + tid];
    out[(size_t)q * CCH + tid] = o;
}

extern "C" void kernel_launch(void* const* d_in, const int* in_sizes, int n_in,
                              void* d_out, int out_size, void* d_ws, size_t ws_size,
                              hipStream_t stream) {
    const float* qp  = (const float*)d_in[0];
    const float* cxz = (const float*)d_in[1];
    const float* cxy = (const float*)d_in[2];
    const float* cyz = (const float*)d_in[3];
    const float* cp  = (const float*)d_in[4];
    const float* Wv  = (const float*)d_in[5];
    const float* bv  = (const float*)d_in[6];
    const float* Ww  = (const float*)d_in[7];
    const float* bw  = (const float*)d_in[8];
    const float* Wo  = (const float*)d_in[9];
    const float* bo  = (const float*)d_in[10];
    float* out = (float*)d_out;

    const int bs = in_sizes[1] / (CCH * NPIX);
    const int ns = in_sizes[0] / (bs * 9);
    const int nq = bs * ns;

    const size_t planeFloats = (size_t)bs * CCH * NPIX;   // per plane
    const size_t needBytes = 3 * planeFloats * sizeof(float);

    if (ws_size >= needBytes) {
        float* t_xz = (float*)d_ws;
        float* t_xy = t_xz + planeFloats;
        float* t_yz = t_xy + planeFloats;

        dim3 tgrid(NPIX / TDIM, CCH / TDIM, bs);
        dim3 tblk(TDIM, 8);
        transpose_cl_kernel<<<tgrid, tblk, 0, stream>>>(cxz, t_xz);
        transpose_cl_kernel<<<tgrid, tblk, 0, stream>>>(cxy, t_xy);
        transpose_cl_kernel<<<tgrid, tblk, 0, stream>>>(cyz, t_yz);

        equi_attn_kernel<true><<<nq, 128, 0, stream>>>(
            qp, t_xz, t_xy, t_yz, cp, Wv, bv, Ww, bw, Wo, bo, out, ns);
    } else {
        equi_attn_kernel<false><<<nq, 128, 0, stream>>>(
            qp, cxz, cxy, cyz, cp, Wv, bv, Ww, bw, Wo, bo, out, ns);
    }
}

// Round 3
// 373.854 us; speedup vs baseline: 12.2449x; 1.2619x over previous
//
#include <hip/hip_runtime.h>
#include <hip/hip_fp16.h>

#define CCH 128      // FEATURE_DIM (channels)
#define HID 128      // HIDDEN
#define NCP 25
#define HH  128      // plane H
#define WW  128      // plane W
#define NPIX (HH * WW)

// ------------- Transpose+convert (B,C,H,W) f32 -> (B,H,W,C) f16 -------------
// Tile 64(n) x 64(c). Block (64,4).
__global__ __launch_bounds__(256) void transpose_f16_kernel(
    const float* __restrict__ s0, const float* __restrict__ s1, const float* __restrict__ s2,
    __half* __restrict__ d0, __half* __restrict__ d1, __half* __restrict__ d2)
{
    __shared__ float tile[64][65];
    const int z = blockIdx.z;           // b*3 + plane
    const int b = z / 3, pl = z - 3 * b;
    const float* src = (pl == 0 ? s0 : pl == 1 ? s1 : s2) + (size_t)b * CCH * NPIX;
    __half* dst      = (pl == 0 ? d0 : pl == 1 ? d1 : d2) + (size_t)b * CCH * NPIX;
    const int n0 = blockIdx.x * 64;
    const int c0 = blockIdx.y * 64;
    const int tx = threadIdx.x;         // 0..63
    const int ty = threadIdx.y;         // 0..3

    #pragma unroll
    for (int cc = 0; cc < 64; cc += 4)
        tile[cc + ty][tx] = src[(size_t)(c0 + cc + ty) * NPIX + (n0 + tx)];
    __syncthreads();
    #pragma unroll
    for (int nn = 0; nn < 64; nn += 4)
        dst[(size_t)(n0 + nn + ty) * CCH + (c0 + tx)] = __float2half(tile[tx][nn + ty]);
}

// ------------- fp16 channel-last bilinear, lane owns channel pair -----------
__device__ __forceinline__ float2 bilin16(const __half* __restrict__ pl, int t, float u, float v) {
    float x = fminf(fmaxf(u, 0.f), 1.f) * (float)(WW - 1);
    float y = fminf(fmaxf(v, 0.f), 1.f) * (float)(HH - 1);
    int x0 = (int)floorf(x); x0 = x0 > (WW - 2) ? (WW - 2) : x0;
    int y0 = (int)floorf(y); y0 = y0 > (HH - 2) ? (HH - 2) : y0;
    float wx = x - (float)x0;
    float wy = y - (float)y0;
    const __half2* p = (const __half2*)(pl) + ((size_t)(y0 * WW + x0) << 6) + t;
    float2 f00 = __half22float2(p[0]);
    float2 f01 = __half22float2(p[64]);
    float2 f10 = __half22float2(p[WW * 64]);
    float2 f11 = __half22float2(p[WW * 64 + 64]);
    float2 r;
    float t0 = f00.x + (f01.x - f00.x) * wx;
    float t1 = f00.y + (f01.y - f00.y) * wx;
    float b0 = f10.x + (f11.x - f10.x) * wx;
    float b1 = f10.y + (f11.y - f10.y) * wx;
    r.x = t0 + (b0 - t0) * wy;
    r.y = t1 + (b1 - t1) * wy;
    return r;
}

// ------------- Main fused kernel: 1 wave per query, 4 queries/block ---------
__global__ __launch_bounds__(256) void equi_attn16_kernel(
    const float* __restrict__ qp,    // (bs, ns, 9)
    const __half* __restrict__ cxz,  // (bs, NPIX, C) f16
    const __half* __restrict__ cxy,
    const __half* __restrict__ cyz,
    const float* __restrict__ cp,    // (NCP, 3)
    const float* __restrict__ Wv,    // (C, HID)
    const float* __restrict__ bv,
    const float* __restrict__ Ww,    // (C, NCP)
    const float* __restrict__ bw,
    const float* __restrict__ Wo,    // (HID, C)
    const float* __restrict__ bo,
    float* __restrict__ out,         // (bs, ns, C)
    int ns)
{
    const int w    = threadIdx.x >> 6;          // wave in block: 0..3
    const int lane = threadIdx.x & 63;          // owns channels 2*lane, 2*lane+1
    const int q    = blockIdx.x * 4 + w;
    const int b    = q / ns;
    const int c0   = lane * 2;

    const size_t planeStride = (size_t)CCH * NPIX;
    const __half* pxz = cxz + (size_t)b * planeStride;
    const __half* pxy = cxy + (size_t)b * planeStride;
    const __half* pyz = cyz + (size_t)b * planeStride;

    const float* qptr = qp + (size_t)q * 9;
    const float px = qptr[0], py = qptr[1], pz = qptr[2];
    const float a1x = qptr[3], a1y = qptr[4], a1z = qptr[5];
    const float a2x = qptr[6], a2y = qptr[7], a2z = qptr[8];

    // rot6d -> matrix
    float n1 = rsqrtf(a1x * a1x + a1y * a1y + a1z * a1z);
    float b1x = a1x * n1, b1y = a1y * n1, b1z = a1z * n1;
    float dd = b1x * a2x + b1y * a2y + b1z * a2z;
    float u2x = a2x - dd * b1x, u2y = a2y - dd * b1y, u2z = a2z - dd * b1z;
    float n2 = rsqrtf(u2x * u2x + u2y * u2y + u2z * u2z);
    float b2x = u2x * n2, b2y = u2y * n2, b2z = u2z * n2;
    float b3x = b1y * b2z - b1z * b2y;
    float b3y = b1z * b2x - b1x * b2z;
    float b3z = b1x * b2y - b1y * b2x;

    __shared__ float sFeat[4][CCH];
    __shared__ float sW[4][32];
    __shared__ float sWsum[4][CCH];
    __shared__ float sPre[4][HID];

    float2 feat = bilin16(pxz, lane, px, pz);
    {
        float2 f = bilin16(pxy, lane, px, py); feat.x += f.x; feat.y += f.y;
        f = bilin16(pyz, lane, py, pz);        feat.x += f.x; feat.y += f.y;
    }
    sFeat[w][c0] = feat.x;
    sFeat[w][c0 + 1] = feat.y;
    __syncthreads();

    // weights[g] = feature . Ww[:,g] + bw[g]   (lanes 0..24 serial)
    if (lane < NCP) {
        float acc = bw[lane];
        #pragma unroll 8
        for (int c = 0; c < CCH; ++c)
            acc += sFeat[w][c] * Ww[c * NCP + lane];
        sW[w][lane] = acc;
    }
    __syncthreads();

    float sw = 0.f;
    #pragma unroll
    for (int g = 0; g < NCP; ++g) sw += sW[w][g];

    // weighted sum over anchors
    float wacc0 = 0.f, wacc1 = 0.f;
    for (int g = 0; g < NCP; ++g) {
        float cx = cp[g * 3 + 0], cy = cp[g * 3 + 1], cz = cp[g * 3 + 2];
        float ax = px + b1x * cx + b1y * cy + b1z * cz;
        float ay = py + b2x * cx + b2y * cy + b2z * cz;
        float az = pz + b3x * cx + b3y * cy + b3z * cz;
        float2 s = bilin16(pxz, lane, ax, az);
        float2 f = bilin16(pxy, lane, ax, ay); s.x += f.x; s.y += f.y;
        f = bilin16(pyz, lane, ay, az);        s.x += f.x; s.y += f.y;
        float wg = sW[w][g];
        wacc0 += wg * s.x;
        wacc1 += wg * s.y;
    }
    sWsum[w][c0] = wacc0;
    sWsum[w][c0 + 1] = wacc1;
    __syncthreads();

    // pre[h] = sw*bv[h] + sum_c wsum[c] * Wv[c][h]   (h pair = c0,c0+1)
    const float2* Wv2 = (const float2*)Wv;
    float pre0 = sw * bv[c0], pre1 = sw * bv[c0 + 1];
    #pragma unroll 8
    for (int c = 0; c < CCH; ++c) {
        float2 wv = Wv2[c * 64 + lane];
        float ws = sWsum[w][c];
        pre0 += ws * wv.x;
        pre1 += ws * wv.y;
    }
    sPre[w][c0] = pre0;
    sPre[w][c0 + 1] = pre1;
    __syncthreads();

    // out[c] = bo[c] + feat[c] + sum_h pre[h] * Wo[h][c]
    const float2* Wo2 = (const float2*)Wo;
    float o0 = bo[c0] + feat.x;
    float o1 = bo[c0 + 1] + feat.y;
    #pragma unroll 8
    for (int h = 0; h < HID; ++h) {
        float2 wo = Wo2[h * 64 + lane];
        float ph = sPre[w][h];
        o0 += ph * wo.x;
        o1 += ph * wo.y;
    }
    float2* out2 = (float2*)(out + (size_t)q * CCH);
    out2[lane] = make_float2(o0, o1);
}

// ------------- Fallback (channel-first fp32, no workspace) ------------------
__device__ __forceinline__ float bilin_cf(const float* __restrict__ pl, int c, float u, float v) {
    float x = fminf(fmaxf(u, 0.f), 1.f) * (float)(WW - 1);
    float y = fminf(fmaxf(v, 0.f), 1.f) * (float)(HH - 1);
    int x0 = (int)floorf(x); x0 = x0 > (WW - 2) ? (WW - 2) : x0;
    int y0 = (int)floorf(y); y0 = y0 > (HH - 2) ? (HH - 2) : y0;
    float wx = x - (float)x0;
    float wy = y - (float)y0;
    const float* p = pl + ((size_t)c << 14) + (y0 << 7) + x0;
    float top = p[0] * (1.f - wx) + p[1] * wx;
    float bot = p[WW] * (1.f - wx) + p[WW + 1] * wx;
    return top * (1.f - wy) + bot * wy;
}

__global__ __launch_bounds__(128) void equi_attn_cf_kernel(
    const float* __restrict__ qp, const float* __restrict__ cxz,
    const float* __restrict__ cxy, const float* __restrict__ cyz,
    const float* __restrict__ cp, const float* __restrict__ Wv,
    const float* __restrict__ bv, const float* __restrict__ Ww,
    const float* __restrict__ bw, const float* __restrict__ Wo,
    const float* __restrict__ bo, float* __restrict__ out, int ns)
{
    const int q = blockIdx.x, b = q / ns, tid = threadIdx.x;
    const size_t planeStride = (size_t)CCH * NPIX;
    const float* pxz = cxz + (size_t)b * planeStride;
    const float* pxy = cxy + (size_t)b * planeStride;
    const float* pyz = cyz + (size_t)b * planeStride;
    const float* qptr = qp + (size_t)q * 9;
    const float px = qptr[0], py = qptr[1], pz = qptr[2];
    const float a1x = qptr[3], a1y = qptr[4], a1z = qptr[5];
    const float a2x = qptr[6], a2y = qptr[7], a2z = qptr[8];
    float n1 = rsqrtf(a1x * a1x + a1y * a1y + a1z * a1z);
    float b1x = a1x * n1, b1y = a1y * n1, b1z = a1z * n1;
    float dd = b1x * a2x + b1y * a2y + b1z * a2z;
    float u2x = a2x - dd * b1x, u2y = a2y - dd * b1y, u2z = a2z - dd * b1z;
    float n2 = rsqrtf(u2x * u2x + u2y * u2y + u2z * u2z);
    float b2x = u2x * n2, b2y = u2y * n2, b2z = u2z * n2;
    float b3x = b1y * b2z - b1z * b2y;
    float b3y = b1z * b2x - b1x * b2z;
    float b3z = b1x * b2y - b1y * b2x;
    __shared__ float sFeat[CCH]; __shared__ float sW[32];
    __shared__ float sWsum[CCH]; __shared__ float sPre[HID];
    float feat = bilin_cf(pxz, tid, px, pz) + bilin_cf(pxy, tid, px, py) + bilin_cf(pyz, tid, py, pz);
    sFeat[tid] = feat;
    __syncthreads();
    if (tid < NCP) {
        float acc = bw[tid];
        for (int c = 0; c < CCH; ++c) acc += sFeat[c] * Ww[c * NCP + tid];
        sW[tid] = acc;
    }
    __syncthreads();
    float sw = 0.f;
    #pragma unroll
    for (int g = 0; g < NCP; ++g) sw += sW[g];
    float wacc = 0.f;
    for (int g = 0; g < NCP; ++g) {
        float cx = cp[g * 3 + 0], cy = cp[g * 3 + 1], cz = cp[g * 3 + 2];
        float ax = px + b1x * cx + b1y * cy + b1z * cz;
        float ay = py + b2x * cx + b2y * cy + b2z * cz;
        float az = pz + b3x * cx + b3y * cy + b3z * cz;
        wacc += sW[g] * (bilin_cf(pxz, tid, ax, az) + bilin_cf(pxy, tid, ax, ay) + bilin_cf(pyz, tid, ay, az));
    }
    sWsum[tid] = wacc;
    __syncthreads();
    float pre = sw * bv[tid];
    for (int c = 0; c < CCH; ++c) pre += sWsum[c] * Wv[c * HID + tid];
    sPre[tid] = pre;
    __syncthreads();
    float o = bo[tid] + feat;
    for (int h = 0; h < HID; ++h) o += sPre[h] * Wo[h * CCH + tid];
    out[(size_t)q * CCH + tid] = o;
}

extern "C" void kernel_launch(void* const* d_in, const int* in_sizes, int n_in,
                              void* d_out, int out_size, void* d_ws, size_t ws_size,
                              hipStream_t stream) {
    const float* qp  = (const float*)d_in[0];
    const float* cxz = (const float*)d_in[1];
    const float* cxy = (const float*)d_in[2];
    const float* cyz = (const float*)d_in[3];
    const float* cp  = (const float*)d_in[4];
    const float* Wv  = (const float*)d_in[5];
    const float* bv  = (const float*)d_in[6];
    const float* Ww  = (const float*)d_in[7];
    const float* bw  = (const float*)d_in[8];
    const float* Wo  = (const float*)d_in[9];
    const float* bo  = (const float*)d_in[10];
    float* out = (float*)d_out;

    const int bs = in_sizes[1] / (CCH * NPIX);
    const int ns = in_sizes[0] / (bs * 9);
    const int nq = bs * ns;

    const size_t planeFloats = (size_t)bs * CCH * NPIX;     // per plane
    const size_t needBytes = 3 * planeFloats * sizeof(__half);

    if (ws_size >= needBytes && (nq % 4) == 0) {
        __half* t_xz = (__half*)d_ws;
        __half* t_xy = t_xz + planeFloats;
        __half* t_yz = t_xy + planeFloats;

        dim3 tgrid(NPIX / 64, CCH / 64, bs * 3);
        dim3 tblk(64, 4);
        transpose_f16_kernel<<<tgrid, tblk, 0, stream>>>(cxz, cxy, cyz, t_xz, t_xy, t_yz);

        equi_attn16_kernel<<<nq / 4, 256, 0, stream>>>(
            qp, t_xz, t_xy, t_yz, cp, Wv, bv, Ww, bw, Wo, bo, out, ns);
    } else {
        equi_attn_cf_kernel<<<nq, 128, 0, stream>>>(
            qp, cxz, cxy, cyz, cp, Wv, bv, Ww, bw, Wo, bo, out, ns);
    }
}

// Round 4
// 336.054 us; speedup vs baseline: 13.6223x; 1.1125x over previous
//
#include <hip/hip_runtime.h>
#include <hip/hip_fp16.h>

#define CCH 128      // FEATURE_DIM (channels)
#define HID 128      // HIDDEN
#define NCP 25
#define HH  128      // plane H
#define WW  128      // plane W
#define NPIX (HH * WW)

// ------------- Transpose+convert (B,C,H,W) f32 -> (B,H,W,C) f16 -------------
__global__ __launch_bounds__(256) void transpose_f16_kernel(
    const float* __restrict__ s0, const float* __restrict__ s1, const float* __restrict__ s2,
    __half* __restrict__ d0, __half* __restrict__ d1, __half* __restrict__ d2)
{
    __shared__ float tile[64][65];
    const int z = blockIdx.z;           // b*3 + plane
    const int b = z / 3, pl = z - 3 * b;
    const float* src = (pl == 0 ? s0 : pl == 1 ? s1 : s2) + (size_t)b * CCH * NPIX;
    __half* dst      = (pl == 0 ? d0 : pl == 1 ? d1 : d2) + (size_t)b * CCH * NPIX;
    const int n0 = blockIdx.x * 64;
    const int c0 = blockIdx.y * 64;
    const int tx = threadIdx.x;         // 0..63
    const int ty = threadIdx.y;         // 0..3

    #pragma unroll
    for (int cc = 0; cc < 64; cc += 4)
        tile[cc + ty][tx] = src[(size_t)(c0 + cc + ty) * NPIX + (n0 + tx)];
    __syncthreads();
    #pragma unroll
    for (int nn = 0; nn < 64; nn += 4)
        dst[(size_t)(n0 + nn + ty) * CCH + (c0 + tx)] = __float2half(tile[tx][nn + ty]);
}

// ------------- sample context: half2 offset + lerp weights ------------------
struct SampCtx { int off; float wx, wy; };

__device__ __forceinline__ SampCtx mkctx(int lane, float u, float v) {
    float x = fminf(fmaxf(u, 0.f), 1.f) * (float)(WW - 1);
    float y = fminf(fmaxf(v, 0.f), 1.f) * (float)(HH - 1);
    int x0 = (int)floorf(x); x0 = x0 > (WW - 2) ? (WW - 2) : x0;
    int y0 = (int)floorf(y); y0 = y0 > (HH - 2) ? (HH - 2) : y0;
    SampCtx c;
    c.wx = x - (float)x0;
    c.wy = y - (float)y0;
    c.off = ((y0 * WW + x0) << 6) + lane;   // units of __half2
    return c;
}

__device__ __forceinline__ float2 lerp22(const __half2 r[4], float wx, float wy) {
    float2 f00 = __half22float2(r[0]);
    float2 f01 = __half22float2(r[1]);
    float2 f10 = __half22float2(r[2]);
    float2 f11 = __half22float2(r[3]);
    float t0 = f00.x + (f01.x - f00.x) * wx;
    float t1 = f00.y + (f01.y - f00.y) * wx;
    float b0 = f10.x + (f11.x - f10.x) * wx;
    float b1 = f10.y + (f11.y - f10.y) * wx;
    float2 r2;
    r2.x = t0 + (b0 - t0) * wy;
    r2.y = t1 + (b1 - t1) * wy;
    return r2;
}

// ------------- Main fused kernel: 1 wave per query, 4 queries/block ---------
__global__ __launch_bounds__(256, 4) void equi_attn16_kernel(
    const float* __restrict__ qp,    // (bs, ns, 9)
    const __half* __restrict__ cxz,  // (bs, NPIX, C) f16
    const __half* __restrict__ cxy,
    const __half* __restrict__ cyz,
    const float* __restrict__ cp,    // (NCP, 3)
    const float* __restrict__ Wv,    // (C, HID)
    const float* __restrict__ bv,
    const float* __restrict__ Ww,    // (C, NCP)
    const float* __restrict__ bw,
    const float* __restrict__ Wo,    // (HID, C)
    const float* __restrict__ bo,
    float* __restrict__ out,         // (bs, ns, C)
    int ns)
{
    const int w    = threadIdx.x >> 6;          // wave in block: 0..3
    const int lane = threadIdx.x & 63;          // owns channels 2*lane, 2*lane+1
    const int q    = blockIdx.x * 4 + w;
    const int b    = q / ns;
    const int c0   = lane * 2;

    const size_t planeStride = (size_t)CCH * NPIX;
    const __half2* P0 = (const __half2*)(cxz + (size_t)b * planeStride);
    const __half2* P1 = (const __half2*)(cxy + (size_t)b * planeStride);
    const __half2* P2 = (const __half2*)(cyz + (size_t)b * planeStride);

    const float* qptr = qp + (size_t)q * 9;
    const float px = qptr[0], py = qptr[1], pz = qptr[2];
    const float a1x = qptr[3], a1y = qptr[4], a1z = qptr[5];
    const float a2x = qptr[6], a2y = qptr[7], a2z = qptr[8];

    // rot6d -> matrix
    float n1 = rsqrtf(a1x * a1x + a1y * a1y + a1z * a1z);
    float b1x = a1x * n1, b1y = a1y * n1, b1z = a1z * n1;
    float dd = b1x * a2x + b1y * a2y + b1z * a2z;
    float u2x = a2x - dd * b1x, u2y = a2y - dd * b1y, u2z = a2z - dd * b1z;
    float n2 = rsqrtf(u2x * u2x + u2y * u2y + u2z * u2z);
    float b2x = u2x * n2, b2y = u2y * n2, b2z = u2z * n2;
    float b3x = b1y * b2z - b1z * b2y;
    float b3y = b1z * b2x - b1x * b2z;
    float b3z = b1x * b2y - b1y * b2x;

    __shared__ float sFeat[4][CCH];
    __shared__ float sW[4][32];
    __shared__ float sWsum[4][CCH];
    __shared__ float sPre[4][HID];

    // ---- feature sample: 3 planes, 12 loads batched ----
    float2 feat;
    {
        SampCtx cc0 = mkctx(lane, px, pz);
        SampCtx cc1 = mkctx(lane, px, py);
        SampCtx cc2 = mkctx(lane, py, pz);
        __half2 r0[4], r1[4], r2[4];
        r0[0] = P0[cc0.off]; r0[1] = P0[cc0.off + 64]; r0[2] = P0[cc0.off + 8192]; r0[3] = P0[cc0.off + 8256];
        r1[0] = P1[cc1.off]; r1[1] = P1[cc1.off + 64]; r1[2] = P1[cc1.off + 8192]; r1[3] = P1[cc1.off + 8256];
        r2[0] = P2[cc2.off]; r2[1] = P2[cc2.off + 64]; r2[2] = P2[cc2.off + 8192]; r2[3] = P2[cc2.off + 8256];
        float2 f0 = lerp22(r0, cc0.wx, cc0.wy);
        float2 f1 = lerp22(r1, cc1.wx, cc1.wy);
        float2 f2 = lerp22(r2, cc2.wx, cc2.wy);
        feat.x = f0.x + f1.x + f2.x;
        feat.y = f0.y + f1.y + f2.y;
    }
    sFeat[w][c0] = feat.x;
    sFeat[w][c0 + 1] = feat.y;
    __syncthreads();

    // weights[g] = feature . Ww[:,g] + bw[g]   (lanes 0..24 serial)
    if (lane < NCP) {
        float acc = bw[lane];
        #pragma unroll 8
        for (int c = 0; c < CCH; ++c)
            acc += sFeat[w][c] * Ww[c * NCP + lane];
        sW[w][lane] = acc;
    }
    __syncthreads();

    float sw = 0.f;
    #pragma unroll
    for (int g = 0; g < NCP; ++g) sw += sW[w][g];

    // ---- anchor loop: 2 anchors per iteration, 24 loads batched ----
    float wacc0 = 0.f, wacc1 = 0.f;
    #pragma unroll 2
    for (int j = 0; j < 12; ++j) {
        const int gA = 2 * j, gB = 2 * j + 1;
        float cyA = cp[gA * 3 + 1], czA = cp[gA * 3 + 2], cxA = cp[gA * 3 + 0];
        float cyB = cp[gB * 3 + 1], czB = cp[gB * 3 + 2], cxB = cp[gB * 3 + 0];
        float axA = px + b1x * cxA + b1y * cyA + b1z * czA;
        float ayA = py + b2x * cxA + b2y * cyA + b2z * czA;
        float azA = pz + b3x * cxA + b3y * cyA + b3z * czA;
        float axB = px + b1x * cxB + b1y * cyB + b1z * czB;
        float ayB = py + b2x * cxB + b2y * cyB + b2z * czB;
        float azB = pz + b3x * cxB + b3y * cyB + b3z * czB;

        SampCtx c0A = mkctx(lane, axA, azA);
        SampCtx c1A = mkctx(lane, axA, ayA);
        SampCtx c2A = mkctx(lane, ayA, azA);
        SampCtx c0B = mkctx(lane, axB, azB);
        SampCtx c1B = mkctx(lane, axB, ayB);
        SampCtx c2B = mkctx(lane, ayB, azB);

        __half2 r0A[4], r1A[4], r2A[4], r0B[4], r1B[4], r2B[4];
        r0A[0] = P0[c0A.off]; r0A[1] = P0[c0A.off + 64]; r0A[2] = P0[c0A.off + 8192]; r0A[3] = P0[c0A.off + 8256];
        r1A[0] = P1[c1A.off]; r1A[1] = P1[c1A.off + 64]; r1A[2] = P1[c1A.off + 8192]; r1A[3] = P1[c1A.off + 8256];
        r2A[0] = P2[c2A.off]; r2A[1] = P2[c2A.off + 64]; r2A[2] = P2[c2A.off + 8192]; r2A[3] = P2[c2A.off + 8256];
        r0B[0] = P0[c0B.off]; r0B[1] = P0[c0B.off + 64]; r0B[2] = P0[c0B.off + 8192]; r0B[3] = P0[c0B.off + 8256];
        r1B[0] = P1[c1B.off]; r1B[1] = P1[c1B.off + 64]; r1B[2] = P1[c1B.off + 8192]; r1B[3] = P1[c1B.off + 8256];
        r2B[0] = P2[c2B.off]; r2B[1] = P2[c2B.off + 64]; r2B[2] = P2[c2B.off + 8192]; r2B[3] = P2[c2B.off + 8256];

        float2 sA = lerp22(r0A, c0A.wx, c0A.wy);
        float2 t  = lerp22(r1A, c1A.wx, c1A.wy); sA.x += t.x; sA.y += t.y;
        t = lerp22(r2A, c2A.wx, c2A.wy);         sA.x += t.x; sA.y += t.y;
        float wgA = sW[w][gA];
        wacc0 += wgA * sA.x;
        wacc1 += wgA * sA.y;

        float2 sB = lerp22(r0B, c0B.wx, c0B.wy);
        t = lerp22(r1B, c1B.wx, c1B.wy);         sB.x += t.x; sB.y += t.y;
        t = lerp22(r2B, c2B.wx, c2B.wy);         sB.x += t.x; sB.y += t.y;
        float wgB = sW[w][gB];
        wacc0 += wgB * sB.x;
        wacc1 += wgB * sB.y;
    }
    {   // anchor 24
        const int g = 24;
        float cx = cp[g * 3 + 0], cy = cp[g * 3 + 1], cz = cp[g * 3 + 2];
        float ax = px + b1x * cx + b1y * cy + b1z * cz;
        float ay = py + b2x * cx + b2y * cy + b2z * cz;
        float az = pz + b3x * cx + b3y * cy + b3z * cz;
        SampCtx cc0 = mkctx(lane, ax, az);
        SampCtx cc1 = mkctx(lane, ax, ay);
        SampCtx cc2 = mkctx(lane, ay, az);
        __half2 r0[4], r1[4], r2[4];
        r0[0] = P0[cc0.off]; r0[1] = P0[cc0.off + 64]; r0[2] = P0[cc0.off + 8192]; r0[3] = P0[cc0.off + 8256];
        r1[0] = P1[cc1.off]; r1[1] = P1[cc1.off + 64]; r1[2] = P1[cc1.off + 8192]; r1[3] = P1[cc1.off + 8256];
        r2[0] = P2[cc2.off]; r2[1] = P2[cc2.off + 64]; r2[2] = P2[cc2.off + 8192]; r2[3] = P2[cc2.off + 8256];
        float2 s = lerp22(r0, cc0.wx, cc0.wy);
        float2 t = lerp22(r1, cc1.wx, cc1.wy); s.x += t.x; s.y += t.y;
        t = lerp22(r2, cc2.wx, cc2.wy);        s.x += t.x; s.y += t.y;
        float wg = sW[w][g];
        wacc0 += wg * s.x;
        wacc1 += wg * s.y;
    }
    sWsum[w][c0] = wacc0;
    sWsum[w][c0 + 1] = wacc1;
    __syncthreads();

    // pre[h] = sw*bv[h] + sum_c wsum[c] * Wv[c][h]
    const float2* Wv2 = (const float2*)Wv;
    float pre0 = sw * bv[c0], pre1 = sw * bv[c0 + 1];
    #pragma unroll 8
    for (int c = 0; c < CCH; ++c) {
        float2 wv = Wv2[c * 64 + lane];
        float ws = sWsum[w][c];
        pre0 += ws * wv.x;
        pre1 += ws * wv.y;
    }
    sPre[w][c0] = pre0;
    sPre[w][c0 + 1] = pre1;
    __syncthreads();

    // out[c] = bo[c] + feat[c] + sum_h pre[h] * Wo[h][c]
    const float2* Wo2 = (const float2*)Wo;
    float o0 = bo[c0] + feat.x;
    float o1 = bo[c0 + 1] + feat.y;
    #pragma unroll 8
    for (int h = 0; h < HID; ++h) {
        float2 wo = Wo2[h * 64 + lane];
        float ph = sPre[w][h];
        o0 += ph * wo.x;
        o1 += ph * wo.y;
    }
    float2* out2 = (float2*)(out + (size_t)q * CCH);
    out2[lane] = make_float2(o0, o1);
}

// ------------- Fallback (channel-first fp32, no workspace) ------------------
__device__ __forceinline__ float bilin_cf(const float* __restrict__ pl, int c, float u, float v) {
    float x = fminf(fmaxf(u, 0.f), 1.f) * (float)(WW - 1);
    float y = fminf(fmaxf(v, 0.f), 1.f) * (float)(HH - 1);
    int x0 = (int)floorf(x); x0 = x0 > (WW - 2) ? (WW - 2) : x0;
    int y0 = (int)floorf(y); y0 = y0 > (HH - 2) ? (HH - 2) : y0;
    float wx = x - (float)x0;
    float wy = y - (float)y0;
    const float* p = pl + ((size_t)c << 14) + (y0 << 7) + x0;
    float top = p[0] * (1.f - wx) + p[1] * wx;
    float bot = p[WW] * (1.f - wx) + p[WW + 1] * wx;
    return top * (1.f - wy) + bot * wy;
}

__global__ __launch_bounds__(128) void equi_attn_cf_kernel(
    const float* __restrict__ qp, const float* __restrict__ cxz,
    const float* __restrict__ cxy, const float* __restrict__ cyz,
    const float* __restrict__ cp, const float* __restrict__ Wv,
    const float* __restrict__ bv, const float* __restrict__ Ww,
    const float* __restrict__ bw, const float* __restrict__ Wo,
    const float* __restrict__ bo, float* __restrict__ out, int ns)
{
    const int q = blockIdx.x, b = q / ns, tid = threadIdx.x;
    const size_t planeStride = (size_t)CCH * NPIX;
    const float* pxz = cxz + (size_t)b * planeStride;
    const float* pxy = cxy + (size_t)b * planeStride;
    const float* pyz = cyz + (size_t)b * planeStride;
    const float* qptr = qp + (size_t)q * 9;
    const float px = qptr[0], py = qptr[1], pz = qptr[2];
    const float a1x = qptr[3], a1y = qptr[4], a1z = qptr[5];
    const float a2x = qptr[6], a2y = qptr[7], a2z = qptr[8];
    float n1 = rsqrtf(a1x * a1x + a1y * a1y + a1z * a1z);
    float b1x = a1x * n1, b1y = a1y * n1, b1z = a1z * n1;
    float dd = b1x * a2x + b1y * a2y + b1z * a2z;
    float u2x = a2x - dd * b1x, u2y = a2y - dd * b1y, u2z = a2z - dd * b1z;
    float n2 = rsqrtf(u2x * u2x + u2y * u2y + u2z * u2z);
    float b2x = u2x * n2, b2y = u2y * n2, b2z = u2z * n2;
    float b3x = b1y * b2z - b1z * b2y;
    float b3y = b1z * b2x - b1x * b2z;
    float b3z = b1x * b2y - b1y * b2x;
    __shared__ float sFeat[CCH]; __shared__ float sW[32];
    __shared__ float sWsum[CCH]; __shared__ float sPre[HID];
    float feat = bilin_cf(pxz, tid, px, pz) + bilin_cf(pxy, tid, px, py) + bilin_cf(pyz, tid, py, pz);
    sFeat[tid] = feat;
    __syncthreads();
    if (tid < NCP) {
        float acc = bw[tid];
        for (int c = 0; c < CCH; ++c) acc += sFeat[c] * Ww[c * NCP + tid];
        sW[tid] = acc;
    }
    __syncthreads();
    float sw = 0.f;
    #pragma unroll
    for (int g = 0; g < NCP; ++g) sw += sW[g];
    float wacc = 0.f;
    for (int g = 0; g < NCP; ++g) {
        float cx = cp[g * 3 + 0], cy = cp[g * 3 + 1], cz = cp[g * 3 + 2];
        float ax = px + b1x * cx + b1y * cy + b1z * cz;
        float ay = py + b2x * cx + b2y * cy + b2z * cz;
        float az = pz + b3x * cx + b3y * cy + b3z * cz;
        wacc += sW[g] * (bilin_cf(pxz, tid, ax, az) + bilin_cf(pxy, tid, ax, ay) + bilin_cf(pyz, tid, ay, az));
    }
    sWsum[tid] = wacc;
    __syncthreads();
    float pre = sw * bv[tid];
    for (int c = 0; c < CCH; ++c) pre += sWsum[c] * Wv[c * HID + tid];
    sPre[tid] = pre;
    __syncthreads();
    float o = bo[tid] + feat;
    for (int h = 0; h < HID; ++h) o += sPre[h] * Wo[h * CCH + tid];
    out[(size_t)q * CCH + tid] = o;
}

extern "C" void kernel_launch(void* const* d_in, const int* in_sizes, int n_in,
                              void* d_out, int out_size, void* d_ws, size_t ws_size,
                              hipStream_t stream) {
    const float* qp  = (const float*)d_in[0];
    const float* cxz = (const float*)d_in[1];
    const float* cxy = (const float*)d_in[2];
    const float* cyz = (const float*)d_in[3];
    const float* cp  = (const float*)d_in[4];
    const float* Wv  = (const float*)d_in[5];
    const float* bv  = (const float*)d_in[6];
    const float* Ww  = (const float*)d_in[7];
    const float* bw  = (const float*)d_in[8];
    const float* Wo  = (const float*)d_in[9];
    const float* bo  = (const float*)d_in[10];
    float* out = (float*)d_out;

    const int bs = in_sizes[1] / (CCH * NPIX);
    const int ns = in_sizes[0] / (bs * 9);
    const int nq = bs * ns;

    const size_t planeFloats = (size_t)bs * CCH * NPIX;     // per plane
    const size_t needBytes = 3 * planeFloats * sizeof(__half);

    if (ws_size >= needBytes && (nq % 4) == 0) {
        __half* t_xz = (__half*)d_ws;
        __half* t_xy = t_xz + planeFloats;
        __half* t_yz = t_xy + planeFloats;

        dim3 tgrid(NPIX / 64, CCH / 64, bs * 3);
        dim3 tblk(64, 4);
        transpose_f16_kernel<<<tgrid, tblk, 0, stream>>>(cxz, cxy, cyz, t_xz, t_xy, t_yz);

        equi_attn16_kernel<<<nq / 4, 256, 0, stream>>>(
            qp, t_xz, t_xy, t_yz, cp, Wv, bv, Ww, bw, Wo, bo, out, ns);
    } else {
        equi_attn_cf_kernel<<<nq, 128, 0, stream>>>(
            qp, cxz, cxy, cyz, cp, Wv, bv, Ww, bw, Wo, bo, out, ns);
    }
}